// Round 2
// baseline (100.792 us; speedup 1.0000x reference)
//
#include <hip/hip_runtime.h>
#include <math.h>

#define HEADS 8
#define BUCKETS 64
#define DIM 64
#define SEQ 8192
#define BH 32
#define ROWS_PER_BUCKET (SEQ / BUCKETS)   // 128
#define EPS 1e-6f
#define INV_T (1.0f / 0.7f)
#define SINKHORN_ITER_COUNT 8

// ---------------------------------------------------------------------------
// Kernel 1: bucket means + positional embedding.
// grid = (BH*BUCKETS, 2): y==0 -> q path, y==1 -> k path. 256 threads.
// Each block reduces 128 rows x 64 dims (float4-vectorized, coalesced).
// ---------------------------------------------------------------------------
__global__ __launch_bounds__(256) void bucket_mean_kernel(
    const float* __restrict__ q, const float* __restrict__ k,
    const float* __restrict__ q_pos, const float* __restrict__ k_pos,
    float* __restrict__ sq, float* __restrict__ sk) {

    const int which = blockIdx.y;            // 0 = q, 1 = k
    const int bh = blockIdx.x >> 6;
    const int bucket = blockIdx.x & 63;
    const float* __restrict__ src = which ? k : q;
    const float* __restrict__ pos = which ? k_pos : q_pos;
    float* __restrict__ dst = which ? sk : sq;

    const int t = threadIdx.x;
    const int c = t & 15;     // float4 chunk: dims [4c, 4c+3]
    const int rg = t >> 4;    // row group 0..15, 8 rows each

    const float4* __restrict__ src4 = (const float4*)src;
    size_t base = ((size_t)bh * SEQ + (size_t)bucket * ROWS_PER_BUCKET + (size_t)rg * 8) * (DIM / 4) + c;

    float4 acc = make_float4(0.f, 0.f, 0.f, 0.f);
#pragma unroll
    for (int rr = 0; rr < 8; ++rr) {
        float4 v = src4[base + (size_t)rr * (DIM / 4)];
        acc.x += v.x; acc.y += v.y; acc.z += v.z; acc.w += v.w;
    }

    __shared__ float4 sm[16][16];
    sm[rg][c] = acc;
    __syncthreads();
#pragma unroll
    for (int s = 8; s > 0; s >>= 1) {
        if (rg < s) {
            float4 o = sm[rg + s][c];
            float4 m = sm[rg][c];
            m.x += o.x; m.y += o.y; m.z += o.z; m.w += o.w;
            sm[rg][c] = m;
        }
        __syncthreads();
    }

    if (rg == 0) {
        const int head = bh & (HEADS - 1);
        float4 p = ((const float4*)pos)[(head * BUCKETS + bucket) * (DIM / 4) + c];
        float4 m = sm[0][c];
        const float inv = 1.0f / (float)ROWS_PER_BUCKET;
        float4 r;
        r.x = m.x * inv + p.x; r.y = m.y * inv + p.y;
        r.z = m.z * inv + p.z; r.w = m.w * inv + p.w;
        ((float4*)dst)[(bh * BUCKETS + bucket) * (DIM / 4) + c] = r;
    }
}

// ---------------------------------------------------------------------------
// Kernel 2: per-bh 64x64 R = sq @ sk^T, gumbel-sinkhorn (8 iters), exp, store.
// grid = BH (32 blocks), 256 threads = 4 waves. All state in LDS.
// sk_s / r_s padded to stride 65 -> column access spreads banks.
// ---------------------------------------------------------------------------
__global__ __launch_bounds__(256) void sinkhorn_kernel(
    const float* __restrict__ sq, const float* __restrict__ sk,
    const float* __restrict__ gumbel, float* __restrict__ out) {

    const int bh = blockIdx.x;
    const int t = threadIdx.x;
    const int lane = t & 63;
    const int w = t >> 6;     // wave 0..3

    __shared__ float sq_s[64][64];   // broadcast-read: no pad needed
    __shared__ float sk_s[64][65];
    __shared__ float r_s[64][65];

    // Stage sq, sk: 1024 float4 each, 256 threads -> 4 apiece.
    const float4* __restrict__ sq4 = (const float4*)(sq + bh * 4096);
    const float4* __restrict__ sk4 = (const float4*)(sk + bh * 4096);
    for (int idx = t; idx < 1024; idx += 256) {
        int row = idx >> 4, ch = idx & 15;
        float4 v = sq4[idx];
        *(float4*)&sq_s[row][ch * 4] = v;            // 16B-aligned (stride 64)
        float4 u = sk4[idx];                          // padded row: scalar stores
        sk_s[row][ch * 4 + 0] = u.x; sk_s[row][ch * 4 + 1] = u.y;
        sk_s[row][ch * 4 + 2] = u.z; sk_s[row][ch * 4 + 3] = u.w;
    }
    __syncthreads();

    // R[i][j] = dot(sq[i], sk[j]); wave w owns rows i = w*16 + ii, lane = j.
    const int j = lane;
    float acc[16];
#pragma unroll
    for (int ii = 0; ii < 16; ++ii) acc[ii] = 0.f;
    for (int d = 0; d < 64; ++d) {
        float skv = sk_s[j][d];
#pragma unroll
        for (int ii = 0; ii < 16; ++ii)
            acc[ii] = fmaf(sq_s[w * 16 + ii][d], skv, acc[ii]);
    }

    const float* __restrict__ g = gumbel + bh * 4096;
#pragma unroll
    for (int ii = 0; ii < 16; ++ii) {
        int i = w * 16 + ii;
        float R = acc[ii];
        float r = (logf(fmaxf(R, 0.f) + EPS) + g[i * 64 + j]) * INV_T;
        r_s[i][j] = r;
    }
    __syncthreads();

    for (int it = 0; it < SINKHORN_ITER_COUNT; ++it) {
        // axis=2: logsumexp over j for each row i
#pragma unroll
        for (int ii = 0; ii < 16; ++ii) {
            int i = w * 16 + ii;
            float x = r_s[i][lane];
            float m = x;
#pragma unroll
            for (int off = 32; off > 0; off >>= 1) m = fmaxf(m, __shfl_xor(m, off));
            float s = expf(x - m);
#pragma unroll
            for (int off = 32; off > 0; off >>= 1) s += __shfl_xor(s, off);
            float lse = m + logf(s);
            r_s[i][lane] = x - lse;
        }
        __syncthreads();
        // axis=1: logsumexp over i for each col jc
#pragma unroll
        for (int jj = 0; jj < 16; ++jj) {
            int jc = w * 16 + jj;
            float x = r_s[lane][jc];
            float m = x;
#pragma unroll
            for (int off = 32; off > 0; off >>= 1) m = fmaxf(m, __shfl_xor(m, off));
            float s = expf(x - m);
#pragma unroll
            for (int off = 32; off > 0; off >>= 1) s += __shfl_xor(s, off);
            float lse = m + logf(s);
            r_s[lane][jc] = x - lse;
        }
        __syncthreads();
    }

    float* __restrict__ o = out + bh * 4096;
#pragma unroll
    for (int ii = 0; ii < 16; ++ii) {
        int i = w * 16 + ii;
        o[i * 64 + lane] = expf(r_s[i][lane]);
    }
}

extern "C" void kernel_launch(void* const* d_in, const int* in_sizes, int n_in,
                              void* d_out, int out_size, void* d_ws, size_t ws_size,
                              hipStream_t stream) {
    const float* q   = (const float*)d_in[0];
    const float* k   = (const float*)d_in[1];
    const float* qpe = (const float*)d_in[2];
    const float* kpe = (const float*)d_in[3];
    const float* gum = (const float*)d_in[4];
    float* out = (float*)d_out;

    float* sq = (float*)d_ws;                 // 32*64*64 floats = 512 KB
    float* sk = sq + BH * BUCKETS * DIM;      // another 512 KB

    bucket_mean_kernel<<<dim3(BH * BUCKETS, 2), 256, 0, stream>>>(q, k, qpe, kpe, sq, sk);
    sinkhorn_kernel<<<BH, 256, 0, stream>>>(sq, sk, gum, out);
}

// Round 3
// 49.272 us; speedup vs baseline: 2.0456x; 2.0456x over previous
//
#include <hip/hip_runtime.h>
#include <math.h>

#define HEADS 8
#define BUCKETS 64
#define DIM 64
#define SEQ 8192
#define BH 32
#define ROWS_PER_BUCKET (SEQ / BUCKETS)   // 128
#define EPS 1e-6f
#define LOG2E 1.4426950408889634f
#define INV_T (1.0f / 0.7f)
#define SINKHORN_ITER_COUNT 8

static __device__ __forceinline__ float fast_exp2(float x) {
#if __has_builtin(__builtin_amdgcn_exp2f)
    return __builtin_amdgcn_exp2f(x);     // v_exp_f32
#else
    return exp2f(x);
#endif
}
static __device__ __forceinline__ float fast_log2(float x) {
#if __has_builtin(__builtin_amdgcn_logf)
    return __builtin_amdgcn_logf(x);      // v_log_f32 (log2)
#else
    return log2f(x);
#endif
}

// ---------------------------------------------------------------------------
// Kernel 1: bucket means + positional embedding. HBM-bound (134 MB), at
// roofline (~22 us). grid=(BH*BUCKETS,2), 256 threads, float4 loads.
// ---------------------------------------------------------------------------
__global__ __launch_bounds__(256) void bucket_mean_kernel(
    const float* __restrict__ q, const float* __restrict__ k,
    const float* __restrict__ q_pos, const float* __restrict__ k_pos,
    float* __restrict__ sq, float* __restrict__ sk) {

    const int which = blockIdx.y;            // 0 = q, 1 = k
    const int bh = blockIdx.x >> 6;
    const int bucket = blockIdx.x & 63;
    const float* __restrict__ src = which ? k : q;
    const float* __restrict__ pos = which ? k_pos : q_pos;
    float* __restrict__ dst = which ? sk : sq;

    const int t = threadIdx.x;
    const int c = t & 15;     // float4 chunk: dims [4c, 4c+3]
    const int rg = t >> 4;    // row group 0..15, 8 rows each

    const float4* __restrict__ src4 = (const float4*)src;
    size_t base = ((size_t)bh * SEQ + (size_t)bucket * ROWS_PER_BUCKET + (size_t)rg * 8) * (DIM / 4) + c;

    float4 acc = make_float4(0.f, 0.f, 0.f, 0.f);
#pragma unroll
    for (int rr = 0; rr < 8; ++rr) {
        float4 v = src4[base + (size_t)rr * (DIM / 4)];
        acc.x += v.x; acc.y += v.y; acc.z += v.z; acc.w += v.w;
    }

    __shared__ float4 sm[16][16];
    sm[rg][c] = acc;
    __syncthreads();
#pragma unroll
    for (int s = 8; s > 0; s >>= 1) {
        if (rg < s) {
            float4 o = sm[rg + s][c];
            float4 m = sm[rg][c];
            m.x += o.x; m.y += o.y; m.z += o.z; m.w += o.w;
            sm[rg][c] = m;
        }
        __syncthreads();
    }

    if (rg == 0) {
        const int head = bh & (HEADS - 1);
        float4 p = ((const float4*)pos)[(head * BUCKETS + bucket) * (DIM / 4) + c];
        float4 m = sm[0][c];
        const float inv = 1.0f / (float)ROWS_PER_BUCKET;
        float4 r;
        r.x = m.x * inv + p.x; r.y = m.y * inv + p.y;
        r.z = m.z * inv + p.z; r.w = m.w * inv + p.w;
        ((float4*)dst)[(bh * BUCKETS + bucket) * (DIM / 4) + c] = r;
    }
}

// ---------------------------------------------------------------------------
// Kernel 2: per-bh R = sq@sk^T, gumbel-sinkhorn in BASE-2 log space.
//   y = r * log2e  =>  exp->v_exp_f32, log->v_log_f32, output = 2^y.
// No max-subtraction: initial y in [-70, +30] (2^y safe in f32); after the
// first row pass all y <= 0. grid=BH, 1024 threads (16 waves), each wave
// owns 4 rows/cols per pass. All state in LDS (stride-65 pad on sk_s/r_s).
// ---------------------------------------------------------------------------
__global__ __launch_bounds__(1024) void sinkhorn_kernel(
    const float* __restrict__ sq, const float* __restrict__ sk,
    const float* __restrict__ gumbel, float* __restrict__ out) {

    const int bh = blockIdx.x;
    const int t = threadIdx.x;
    const int lane = t & 63;
    const int w = t >> 6;     // wave 0..15

    __shared__ float sq_s[64][64];   // broadcast-read: no pad needed
    __shared__ float sk_s[64][65];
    __shared__ float r_s[64][65];

    // Stage sq, sk: 1024 float4 each, one per thread.
    {
        const float4* __restrict__ sq4 = (const float4*)(sq + bh * 4096);
        const float4* __restrict__ sk4 = (const float4*)(sk + bh * 4096);
        int row = t >> 4, ch = t & 15;
        float4 v = sq4[t];
        *(float4*)&sq_s[row][ch * 4] = v;
        float4 u = sk4[t];                   // padded row: scalar stores
        sk_s[row][ch * 4 + 0] = u.x; sk_s[row][ch * 4 + 1] = u.y;
        sk_s[row][ch * 4 + 2] = u.z; sk_s[row][ch * 4 + 3] = u.w;
    }
    __syncthreads();

    // R[i][j], wave w owns rows i = w*4+ii, lane = j.
    float acc[4];
#pragma unroll
    for (int ii = 0; ii < 4; ++ii) acc[ii] = 0.f;
    for (int d = 0; d < 64; ++d) {
        float skv = sk_s[lane][d];
#pragma unroll
        for (int ii = 0; ii < 4; ++ii)
            acc[ii] = fmaf(sq_s[w * 4 + ii][d], skv, acc[ii]);
    }

    // y = (log2(relu(R)+eps) + g*log2e) / T
    const float* __restrict__ g = gumbel + bh * 4096;
#pragma unroll
    for (int ii = 0; ii < 4; ++ii) {
        int i = w * 4 + ii;
        float Rp = fmaxf(acc[ii], 0.f) + EPS;
        float y = (fast_log2(Rp) + g[i * 64 + lane] * LOG2E) * INV_T;
        r_s[i][lane] = y;
    }
    __syncthreads();

    for (int it = 0; it < SINKHORN_ITER_COUNT; ++it) {
        // axis=2 (rows): y -= log2(sum_j 2^y)
#pragma unroll
        for (int ii = 0; ii < 4; ++ii) {
            int i = w * 4 + ii;
            float x = r_s[i][lane];
            float s = fast_exp2(x);
#pragma unroll
            for (int off = 32; off > 0; off >>= 1) s += __shfl_xor(s, off);
            r_s[i][lane] = x - fast_log2(s);
        }
        __syncthreads();
        // axis=1 (cols): y -= log2(sum_i 2^y)
#pragma unroll
        for (int jj = 0; jj < 4; ++jj) {
            int jc = w * 4 + jj;
            float x = r_s[lane][jc];
            float s = fast_exp2(x);
#pragma unroll
            for (int off = 32; off > 0; off >>= 1) s += __shfl_xor(s, off);
            r_s[lane][jc] = x - fast_log2(s);
        }
        __syncthreads();
    }

    // out = exp(r) = 2^y
    float* __restrict__ o = out + bh * 4096;
#pragma unroll
    for (int ii = 0; ii < 4; ++ii) {
        int i = w * 4 + ii;
        o[i * 64 + lane] = fast_exp2(r_s[i][lane]);
    }
}

extern "C" void kernel_launch(void* const* d_in, const int* in_sizes, int n_in,
                              void* d_out, int out_size, void* d_ws, size_t ws_size,
                              hipStream_t stream) {
    const float* q   = (const float*)d_in[0];
    const float* k   = (const float*)d_in[1];
    const float* qpe = (const float*)d_in[2];
    const float* kpe = (const float*)d_in[3];
    const float* gum = (const float*)d_in[4];
    float* out = (float*)d_out;

    float* sq = (float*)d_ws;                 // 32*64*64 floats = 512 KB
    float* sk = sq + BH * BUCKETS * DIM;      // another 512 KB

    bucket_mean_kernel<<<dim3(BH * BUCKETS, 2), 256, 0, stream>>>(q, k, qpe, kpe, sq, sk);
    sinkhorn_kernel<<<BH, 1024, 0, stream>>>(sq, sk, gum, out);
}